// Round 6
// baseline (100.954 us; speedup 1.0000x reference)
//
#include <hip/hip_runtime.h>

// ---------------------------------------------------------------------------
// PolyDecoder: out[4096,64] = polyfeats(z)[4096,37449] @ W^T + b
// f16 MFMA GEMM, A generated on the fly from registers (branch-free unrolled
// 32-step degree-aligned K-slices), B pre-tiled in ws, two-phase output
// (plain stores of per-slice partials + reduction kernel; NO atomics).
//
// Padded K layout (32-granular; W padded with zeros):
//   kpad [0,8)=z | 8=const(bias folded) | [9,32)=0 | [32,96)=z^2 |
//   [96,608)=z^3 | [608,4704)=z^4 | [4704,37472)=z^5 | [37472,37504)=0
// step s = kpad/32: 0 deg<=1 | 1..2 deg2 | 3..18 deg3 | 19..146 deg4 |
//                   147..1170 deg5 | 1171 pad (never computed)
//
// Grid: (32 m-blocks of 128 rows) x (KY=37 equal K-slices) = 1184 blocks
//   ky in [0,32):  deg5 slice, sbase = 147 + 32*ky, branch-free
//   ky in [32,36): deg4 slice, sbase = 19 + 32*(ky-32), branch-free
//   ky == 36:      steps 0..18 (deg 0..3), branchy fallback
// Block: 256 thr = 4 waves; wave (g=w>>1, h=w&1): rows [g*64,g*64+64) x
//   cols [h*32,h*32+32): 8 mfma_f32_16x16x32_f16 / step.
// VGPR ~60 -> 8 waves/SIMD allowed; 4.6 blocks/CU all co-resident (TLP).
// ---------------------------------------------------------------------------

#define TOTAL_TERMS 37449
#define NSTEP 1172
#define MBLK 32
#define KY 37
#define OUT_ELEMS 262144            // 4096*64

typedef _Float16 half8 __attribute__((ext_vector_type(8)));
typedef float f32x4 __attribute__((ext_vector_type(4)));

// Coalesced tiled transpose W (f32, n-major) -> Wt (f16 fragments).
// Fragment element (s,nt,lane,j) = W[nt*16+(lane&15)][orig(s*32+(lane>>4)*8+j)]
__global__ __launch_bounds__(256) void convert_w(const float* __restrict__ W,
                                                 const float* __restrict__ bias,
                                                 _Float16* __restrict__ Wt) {
    __shared__ _Float16 lds[64][72];
    int tid  = threadIdx.x;
    int lane = tid & 63;
    int nq   = tid >> 6;               // 0..3
    int kb   = blockIdx.x * 64;
    int kp   = kb + lane;

    int o, mode;                       // mode: 0=load W, 1=zero, 2=const+bias
    if (kp < 8)           { o = 1 + kp;            mode = 0; }
    else if (kp == 8)     { o = 0;                 mode = 2; }
    else if (kp < 32)     { o = 0;                 mode = 1; }
    else if (kp < 96)     { o = 9    + (kp - 32);  mode = 0; }
    else if (kp < 608)    { o = 73   + (kp - 96);  mode = 0; }
    else if (kp < 4704)   { o = 585  + (kp - 608); mode = 0; }
    else if (kp < 37472)  { o = 4681 + (kp - 4704);mode = 0; }
    else                  { o = 0;                 mode = 1; }

#pragma unroll
    for (int r = 0; r < 16; ++r) {
        int n = r * 4 + nq;
        const float* wrow = W + (size_t)n * TOTAL_TERMS;
        float v;
        if (mode == 1)      v = 0.f;
        else if (mode == 2) v = wrow[0] + bias[n];
        else                v = wrow[o];             // coalesced along lane
        lds[n][lane] = (_Float16)v;
    }
    __syncthreads();

    int quad = lane >> 4, l16 = lane & 15;
    int n = nq * 16 + l16;
#pragma unroll
    for (int sl = 0; sl < 2; ++sl) {
        int kk = sl * 32 + quad * 8;
        half8 hv;
#pragma unroll
        for (int j = 0; j < 8; ++j) hv[j] = lds[n][kk + j];
        int s = (kb >> 5) + sl;
        *(half8*)(Wt + ((size_t)(s * 4 + nq) * 64 + lane) * 8) = hv;  // coalesced
    }
}

__global__ __launch_bounds__(256, 4) void poly_gemm(const float* __restrict__ z,
                                                    const _Float16* __restrict__ Wt,
                                                    float* __restrict__ part,
                                                    float* __restrict__ out,
                                                    int use_atomic) {
    __shared__ __align__(16) _Float16 zm[128][8];   // sample-major
    __shared__ _Float16 zT[8][144];                 // digit-major (setup reads only)

    int tid  = threadIdx.x;
    int lane = tid & 63;
    int w    = tid >> 6;
    int g    = w >> 1;                 // m-group: rows g*64..g*64+63
    int h    = w & 1;                  // n-group: cols h*32..h*32+31
    int mb   = blockIdx.x;
    int ky   = blockIdx.y;

    if (tid < 128) {
        const float* zp = z + ((size_t)(mb * 128 + tid)) * 8;
        float4 a = *(const float4*)zp;
        float4 b4 = *(const float4*)(zp + 4);
        half8 hz;
        hz[0] = (_Float16)a.x;  hz[1] = (_Float16)a.y;
        hz[2] = (_Float16)a.z;  hz[3] = (_Float16)a.w;
        hz[4] = (_Float16)b4.x; hz[5] = (_Float16)b4.y;
        hz[6] = (_Float16)b4.z; hz[7] = (_Float16)b4.w;
        *(half8*)&zm[tid][0] = hz;
#pragma unroll
        for (int j = 0; j < 8; ++j) zT[j][tid] = hz[j];
    }
    __syncthreads();

    int quad = lane >> 4;
    int l16  = lane & 15;
    int mrow[4];
    half8 zv[4];
    _Float16 zq[4], zq4[4];
#pragma unroll
    for (int t = 0; t < 4; ++t) {
        mrow[t] = g * 64 + t * 16 + l16;
        zv[t]   = *(const half8*)&zm[mrow[t]][0];
        zq[t]   = zT[quad][mrow[t]];       // z[quad]
        zq4[t]  = zT[quad + 4][mrow[t]];   // z[quad+4]
    }

    f32x4 acc[4][2];
#pragma unroll
    for (int t = 0; t < 4; ++t)
#pragma unroll
        for (int k = 0; k < 2; ++k) acc[t][k] = (f32x4){0.f, 0.f, 0.f, 0.f};

    const _Float16* base = Wt + (size_t)h * 1024 + (size_t)lane * 8;

    auto loadB = [&](int s, half8* B) {
        const _Float16* p = base + (size_t)s * 2048;
        B[0] = *(const half8*)p;
        B[1] = *(const half8*)(p + 512);
    };
    auto mfma8 = [&](const half8* av, const half8* B) {
#pragma unroll
        for (int t = 0; t < 4; ++t)
#pragma unroll
            for (int k = 0; k < 2; ++k)
                acc[t][k] = __builtin_amdgcn_mfma_f32_16x16x32_f16(
                    av[t], B[k], acc[t][k], 0, 0, 0);
    };

    if (ky < 36) {
        // ---- branch-free degree-aligned 32-step slice, fully unrolled ----
        const bool d5 = (ky < 32);
        const int  j  = d5 ? ky : (ky - 32);
        const int  sbase = d5 ? (147 + 32 * j) : (19 + 32 * j);

        _Float16 a1[4];
        if (d5) {
            int r1 = (j >> 2) & 7;                 // z[i1], fixed over slice
#pragma unroll
            for (int t = 0; t < 4; ++t) a1[t] = zT[r1][mrow[t]];
        }

        half8 B0[2], B1[2];
        loadB(sbase, B0);
        loadB(sbase + 1, B1);

#pragma unroll
        for (int h16 = 0; h16 < 2; ++h16) {
            int r2 = (2 * j + h16) & 7;            // changes per 16 steps
            _Float16 gz[4];
#pragma unroll
            for (int t = 0; t < 4; ++t) {
                _Float16 v = zT[r2][mrow[t]];
                gz[t] = d5 ? (_Float16)(a1[t] * v) : v;
            }
            int sh = sbase + h16 * 16;
#pragma unroll
            for (int i2 = 0; i2 < 16; i2 += 2) {
                half8 av[4];
#pragma unroll
                for (int t = 0; t < 4; ++t) {
                    _Float16 f = gz[t] * zv[t][i2 >> 1] * zq[t];
#pragma unroll
                    for (int e = 0; e < 8; ++e) av[t][e] = zv[t][e] * f;
                }
                mfma8(av, B0);
                loadB(sh + i2 + 2, B0);   // unconditional; Wt padded +4 steps
#pragma unroll
                for (int t = 0; t < 4; ++t) {
                    _Float16 f = gz[t] * zv[t][i2 >> 1] * zq4[t];
#pragma unroll
                    for (int e = 0; e < 8; ++e) av[t][e] = zv[t][e] * f;
                }
                mfma8(av, B1);
                loadB(sh + i2 + 3, B1);
            }
        }
    } else {
        // ---- fallback: steps 0..18 (deg 0,2,3) ----
        auto genA = [&](int s, half8* av) {
            if (s == 0) {
#pragma unroll
                for (int t = 0; t < 4; ++t) {
                    if (quad == 0)      av[t] = zv[t];
                    else if (quad == 1) { av[t] = (half8){}; av[t][0] = (_Float16)1.f; }
                    else                av[t] = (half8){};
                }
                return;
            }
            _Float16 f[4];
            if (s >= 3) {
                int u = s - 3;
                int r1 = (u >> 1) & 7;
                int r2 = ((u & 1) << 2) + quad;
#pragma unroll
                for (int t = 0; t < 4; ++t)
                    f[t] = zT[r1][mrow[t]] * zT[r2][mrow[t]];
            } else {
                int r1 = (s - 1) * 4 + quad;
#pragma unroll
                for (int t = 0; t < 4; ++t)
                    f[t] = zT[r1][mrow[t]];
            }
#pragma unroll
            for (int t = 0; t < 4; ++t)
#pragma unroll
                for (int e = 0; e < 8; ++e) av[t][e] = zv[t][e] * f[t];
        };

        half8 B0[2], B1[2];
        loadB(0, B0);
        loadB(1, B1);
        int s = 0;
        for (; s + 1 < 19; s += 2) {
            half8 av[4];
            genA(s, av);
            mfma8(av, B0);
            if (s + 2 < 19) loadB(s + 2, B0);
            genA(s + 1, av);
            mfma8(av, B1);
            if (s + 3 < 19) loadB(s + 3, B1);
        }
        {   // s == 18
            half8 av[4];
            genA(18, av);
            mfma8(av, B0);
        }
    }

    // epilogue: C/D layout col=lane&15, row=(lane>>4)*4+reg
    float* dstbase = use_atomic ? out : (part + (size_t)ky * OUT_ELEMS);
#pragma unroll
    for (int t = 0; t < 4; ++t) {
        int mbase = mb * 128 + g * 64 + t * 16 + quad * 4;
#pragma unroll
        for (int k = 0; k < 2; ++k) {
            int col = h * 32 + k * 16 + l16;
#pragma unroll
            for (int r = 0; r < 4; ++r) {
                size_t idx = (size_t)(mbase + r) * 64 + col;
                if (use_atomic) unsafeAtomicAdd(dstbase + idx, acc[t][k][r]);
                else            dstbase[idx] = acc[t][k][r];
            }
        }
    }
}

// Phase 2: out[i] = sum_ky part[ky][i]  (vectorized float4)
__global__ __launch_bounds__(256) void reduce_part(const float* __restrict__ part,
                                                   float* __restrict__ out) {
    int gid = blockIdx.x * 256 + threadIdx.x;      // 65536 float4s
    const f32x4* p4 = (const f32x4*)part;
    f32x4 s = (f32x4){0.f, 0.f, 0.f, 0.f};
#pragma unroll
    for (int j = 0; j < KY; ++j)
        s += p4[(size_t)j * (OUT_ELEMS / 4) + gid];
    ((f32x4*)out)[gid] = s;
}

extern "C" void kernel_launch(void* const* d_in, const int* in_sizes, int n_in,
                              void* d_out, int out_size, void* d_ws, size_t ws_size,
                              hipStream_t stream) {
    (void)in_sizes; (void)n_in;
    const float* z = (const float*)d_in[0];
    const float* W = (const float*)d_in[1];
    const float* b = (const float*)d_in[2];
    float* out = (float*)d_out;

    const size_t part_bytes = (size_t)KY * OUT_ELEMS * sizeof(float);  // 38.8 MB
    const size_t wt_bytes   = (size_t)(NSTEP + 4) * 2048 * sizeof(_Float16);
    const bool two_phase = ws_size >= part_bytes + wt_bytes;

    float* part;
    _Float16* Wt;
    if (two_phase) {
        part = (float*)d_ws;
        Wt   = (_Float16*)((char*)d_ws + part_bytes);
    } else {
        part = out;                    // unused in atomic mode
        Wt   = (_Float16*)d_ws;
    }

    if (!two_phase)
        hipMemsetAsync(d_out, 0, (size_t)out_size * sizeof(float), stream);
    hipLaunchKernelGGL(convert_w, dim3(NSTEP / 2), dim3(256), 0, stream, W, b, Wt);
    hipLaunchKernelGGL(poly_gemm, dim3(MBLK, KY), dim3(256), 0, stream,
                       z, Wt, part, out, two_phase ? 0 : 1);
    if (two_phase)
        hipLaunchKernelGGL(reduce_part, dim3(OUT_ELEMS / 4 / 256), dim3(256), 0,
                           stream, part, out);
}

// Round 7
// 98.555 us; speedup vs baseline: 1.0243x; 1.0243x over previous
//
#include <hip/hip_runtime.h>

// ---------------------------------------------------------------------------
// PolyDecoder: out[4096,64] = polyfeats(z)[4096,37449] @ W^T + b
// f16 MFMA GEMM, A generated on the fly from registers; B staged via async
// global_load_lds (16 KB chunks, double-buffered) to tolerate HBM latency;
// nontemporal partial stores (keep Wt L2-resident); two-phase reduction.
//
// Padded K layout (32-granular; W padded with zeros):
//   kpad [0,8)=z | 8=const(bias folded) | [9,32)=0 | [32,96)=z^2 |
//   [96,608)=z^3 | [608,4704)=z^4 | [4704,37472)=z^5 | [37472,37504)=0
// step s = kpad/32: 0 deg<=1 | 1..2 deg2 | 3..18 deg3 | 19..146 deg4 |
//                   147..1170 deg5 | 1171 pad (never computed)
//
// Grid (ky fast for XCD locality): (KY=21) x (32 m-blocks of 128 rows)
//   ky in [0,16):  deg5 slice, sb = 147 + 64*ky, 64 steps (4 super-chunks)
//   ky in [16,20): deg4 slice, sb = 19 + 32*(ky-16), 32 steps (2 super-chunks)
//   ky == 20:      steps 0..18 (deg 0..3), branchy fallback
// Block: 4 waves; wave (g=w>>1, h=w&1): rows [g*64,+64) x cols [h*32,+32)
//   -> 8 mfma_f32_16x16x32_f16 / step. Chunk = 4 steps = 16 KB LDS.
// ---------------------------------------------------------------------------

#define TOTAL_TERMS 37449
#define NSTEP 1172
#define MBLK 32
#define KY 21
#define OUT_ELEMS 262144            // 4096*64

typedef _Float16 half8 __attribute__((ext_vector_type(8)));
typedef float f32x4 __attribute__((ext_vector_type(4)));

// Coalesced tiled transpose W (f32, n-major) -> Wt (f16 fragments).
// Fragment element (s,nt,lane,j) = W[nt*16+(lane&15)][orig(s*32+(lane>>4)*8+j)]
__global__ __launch_bounds__(256) void convert_w(const float* __restrict__ W,
                                                 const float* __restrict__ bias,
                                                 _Float16* __restrict__ Wt) {
    __shared__ _Float16 lds[64][72];
    int tid  = threadIdx.x;
    int lane = tid & 63;
    int nq   = tid >> 6;               // 0..3
    int kb   = blockIdx.x * 64;
    int kp   = kb + lane;

    int o, mode;                       // 0=load W, 1=zero, 2=const+bias
    if (kp < 8)           { o = 1 + kp;            mode = 0; }
    else if (kp == 8)     { o = 0;                 mode = 2; }
    else if (kp < 32)     { o = 0;                 mode = 1; }
    else if (kp < 96)     { o = 9    + (kp - 32);  mode = 0; }
    else if (kp < 608)    { o = 73   + (kp - 96);  mode = 0; }
    else if (kp < 4704)   { o = 585  + (kp - 608); mode = 0; }
    else if (kp < 37472)  { o = 4681 + (kp - 4704);mode = 0; }
    else                  { o = 0;                 mode = 1; }

#pragma unroll
    for (int r = 0; r < 16; ++r) {
        int n = r * 4 + nq;
        const float* wrow = W + (size_t)n * TOTAL_TERMS;
        float v;
        if (mode == 1)      v = 0.f;
        else if (mode == 2) v = wrow[0] + bias[n];
        else                v = wrow[o];             // coalesced along lane
        lds[n][lane] = (_Float16)v;
    }
    __syncthreads();

    int quad = lane >> 4, l16 = lane & 15;
    int n = nq * 16 + l16;
#pragma unroll
    for (int sl = 0; sl < 2; ++sl) {
        int kk = sl * 32 + quad * 8;
        half8 hv;
#pragma unroll
        for (int j = 0; j < 8; ++j) hv[j] = lds[n][kk + j];
        int s = (kb >> 5) + sl;
        *(half8*)(Wt + ((size_t)(s * 4 + nq) * 64 + lane) * 8) = hv;  // coalesced
    }
}

__global__ __launch_bounds__(256, 4) void poly_gemm(const float* __restrict__ z,
                                                    const _Float16* __restrict__ Wt,
                                                    float* __restrict__ part,
                                                    float* __restrict__ out,
                                                    int use_atomic) {
    __shared__ __align__(16) _Float16 bbuf[2][8192];   // 2 x 16 KB (4 steps each)
    __shared__ __align__(16) _Float16 zm[128][8];      // sample-major
    __shared__ _Float16 zT[8][144];                    // digit-major

    int tid  = threadIdx.x;
    int lane = tid & 63;
    int w    = tid >> 6;
    int g    = w >> 1;                 // rows [g*64, g*64+64)
    int h    = w & 1;                  // cols [h*32, h*32+32)
    int ky   = blockIdx.x;
    int mb   = blockIdx.y;

    if (tid < 128) {
        const float* zp = z + ((size_t)(mb * 128 + tid)) * 8;
        float4 a = *(const float4*)zp;
        float4 b4 = *(const float4*)(zp + 4);
        half8 hz;
        hz[0] = (_Float16)a.x;  hz[1] = (_Float16)a.y;
        hz[2] = (_Float16)a.z;  hz[3] = (_Float16)a.w;
        hz[4] = (_Float16)b4.x; hz[5] = (_Float16)b4.y;
        hz[6] = (_Float16)b4.z; hz[7] = (_Float16)b4.w;
        *(half8*)&zm[tid][0] = hz;
#pragma unroll
        for (int j = 0; j < 8; ++j) zT[j][tid] = hz[j];
    }
    __syncthreads();

    int quad = lane >> 4;
    int l16  = lane & 15;
    int mrow[4];
    half8 zv[4];
    _Float16 zq[4], zq4[4];
#pragma unroll
    for (int t = 0; t < 4; ++t) {
        mrow[t] = g * 64 + t * 16 + l16;
        zv[t]   = *(const half8*)&zm[mrow[t]][0];
        zq[t]   = zT[quad][mrow[t]];       // z[quad]
        zq4[t]  = zT[quad + 4][mrow[t]];   // z[quad+4]
    }

    f32x4 acc[4][2];
#pragma unroll
    for (int t = 0; t < 4; ++t)
#pragma unroll
        for (int k = 0; k < 2; ++k) acc[t][k] = (f32x4){0.f, 0.f, 0.f, 0.f};

    const int sb = (ky < 16) ? (147 + 64 * ky)
                 : (ky < 20) ? (19 + 32 * (ky - 16)) : 0;

    // Async-stage chunk gc (4 steps = 16 pieces of 1 KB); wave w does 4 pieces.
    auto stage = [&](int gc, int parity) {
        int pbase = (sb + gc * 4) * 4;     // piece index base in (s*4+frag) units
        _Float16* lb = &bbuf[parity][0];
#pragma unroll
        for (int i = 0; i < 4; ++i) {
            int piece = w * 4 + i;
            const _Float16* gp = Wt + ((size_t)(pbase + piece) << 9) + lane * 8;
            __builtin_amdgcn_global_load_lds(
                (const __attribute__((address_space(1))) void*)gp,
                (__attribute__((address_space(3))) void*)(lb + piece * 512 + lane * 8),
                16, 0, 0);
        }
    };
    auto readB = [&](int parity, int ii, half8* B) {
        const _Float16* p = &bbuf[parity][(ii * 4 + 2 * h) * 512 + lane * 8];
        B[0] = *(const half8*)p;
        B[1] = *(const half8*)(p + 512);
    };
    auto mfma8 = [&](const half8* av, const half8* B) {
#pragma unroll
        for (int t = 0; t < 4; ++t)
#pragma unroll
            for (int k = 0; k < 2; ++k)
                acc[t][k] = __builtin_amdgcn_mfma_f32_16x16x32_f16(
                    av[t], B[k], acc[t][k], 0, 0, 0);
    };

    if (ky < 20) {
        const bool d5     = (ky < 16);
        const int  r2base = d5 ? 4 * ky : 2 * (ky - 16);
        const int  nsc    = d5 ? 4 : 2;        // super-chunks of 16 steps
        const int  ntot   = nsc * 4;           // chunks of 4 steps

        _Float16 a1[4];
        if (d5) {
            int r1 = (ky >> 1) & 7;
#pragma unroll
            for (int t = 0; t < 4; ++t) a1[t] = zT[r1][mrow[t]];
        }

        stage(0, 0);
        for (int sc = 0; sc < nsc; ++sc) {
            int rtop = (r2base + sc) & 7;
            _Float16 gz[4];
#pragma unroll
            for (int t = 0; t < 4; ++t) {
                _Float16 v = zT[rtop][mrow[t]];
                gz[t] = d5 ? (_Float16)(a1[t] * v) : v;
            }
#pragma unroll
            for (int cc = 0; cc < 4; ++cc) {
                __syncthreads();               // buf[cc&1] staged & safe
                int gc = sc * 4 + cc;
                if (gc + 1 < ntot) stage(gc + 1, (cc + 1) & 1);
#pragma unroll
                for (int ii = 0; ii < 4; ++ii) {
                    half8 B[2];
                    readB(cc & 1, ii, B);
                    const int r3 = 2 * cc + (ii >> 1);   // compile-time
                    half8 av[4];
#pragma unroll
                    for (int t = 0; t < 4; ++t) {
                        _Float16 f = gz[t] * zv[t][r3] *
                                     ((ii & 1) ? zq4[t] : zq[t]);
#pragma unroll
                        for (int e = 0; e < 8; ++e) av[t][e] = zv[t][e] * f;
                    }
                    mfma8(av, B);
                }
            }
        }
    } else {
        // ---- fallback: steps 0..18 (deg 0,2,3), 5 chunks, last partial ----
        auto genA = [&](int s, half8* av) {
            if (s == 0) {
#pragma unroll
                for (int t = 0; t < 4; ++t) {
                    if (quad == 0)      av[t] = zv[t];
                    else if (quad == 1) { av[t] = (half8){}; av[t][0] = (_Float16)1.f; }
                    else                av[t] = (half8){};
                }
                return;
            }
            _Float16 f[4];
            if (s >= 3) {
                int u = s - 3;
                int r1 = (u >> 1) & 7;
                int r2 = ((u & 1) << 2) + quad;
#pragma unroll
                for (int t = 0; t < 4; ++t)
                    f[t] = zT[r1][mrow[t]] * zT[r2][mrow[t]];
            } else {
                int r1 = (s - 1) * 4 + quad;
#pragma unroll
                for (int t = 0; t < 4; ++t)
                    f[t] = zT[r1][mrow[t]];
            }
#pragma unroll
            for (int t = 0; t < 4; ++t)
#pragma unroll
                for (int e = 0; e < 8; ++e) av[t][e] = zv[t][e] * f[t];
        };

        stage(0, 0);
        for (int gc = 0; gc < 5; ++gc) {
            __syncthreads();
            if (gc + 1 < 5) stage(gc + 1, (gc + 1) & 1);
            int nst = (gc == 4) ? 3 : 4;
            for (int ii = 0; ii < nst; ++ii) {
                half8 B[2];
                readB(gc & 1, ii, B);
                half8 av[4];
                genA(gc * 4 + ii, av);
                mfma8(av, B);
            }
        }
    }

    // epilogue: C/D layout col=lane&15, row=(lane>>4)*4+reg
    float* dstbase = use_atomic ? out : (part + (size_t)ky * OUT_ELEMS);
#pragma unroll
    for (int t = 0; t < 4; ++t) {
        int mbase = mb * 128 + g * 64 + t * 16 + quad * 4;
#pragma unroll
        for (int k = 0; k < 2; ++k) {
            int col = h * 32 + k * 16 + l16;
#pragma unroll
            for (int r = 0; r < 4; ++r) {
                size_t idx = (size_t)(mbase + r) * 64 + col;
                if (use_atomic) unsafeAtomicAdd(out + idx, acc[t][k][r]);
                else __builtin_nontemporal_store(acc[t][k][r], dstbase + idx);
            }
        }
    }
}

// Phase 2: out[i] = sum_ky part[ky][i]  (vectorized, nontemporal)
__global__ __launch_bounds__(256) void reduce_part(const float* __restrict__ part,
                                                   float* __restrict__ out) {
    int gid = blockIdx.x * 256 + threadIdx.x;      // 65536 float4s
    const f32x4* p4 = (const f32x4*)part;
    f32x4 s = (f32x4){0.f, 0.f, 0.f, 0.f};
#pragma unroll
    for (int j = 0; j < KY; ++j)
        s += __builtin_nontemporal_load(p4 + (size_t)j * (OUT_ELEMS / 4) + gid);
    __builtin_nontemporal_store(s, ((f32x4*)out) + gid);
}

extern "C" void kernel_launch(void* const* d_in, const int* in_sizes, int n_in,
                              void* d_out, int out_size, void* d_ws, size_t ws_size,
                              hipStream_t stream) {
    (void)in_sizes; (void)n_in;
    const float* z = (const float*)d_in[0];
    const float* W = (const float*)d_in[1];
    const float* b = (const float*)d_in[2];
    float* out = (float*)d_out;

    const size_t part_bytes = (size_t)KY * OUT_ELEMS * sizeof(float);  // 22 MB
    const size_t wt_bytes   = (size_t)(NSTEP + 4) * 2048 * sizeof(_Float16);
    const bool two_phase = ws_size >= part_bytes + wt_bytes;

    float* part;
    _Float16* Wt;
    if (two_phase) {
        part = (float*)d_ws;
        Wt   = (_Float16*)((char*)d_ws + part_bytes);
    } else {
        part = out;                    // unused in atomic mode
        Wt   = (_Float16*)d_ws;
    }

    if (!two_phase)
        hipMemsetAsync(d_out, 0, (size_t)out_size * sizeof(float), stream);
    hipLaunchKernelGGL(convert_w, dim3(NSTEP / 2), dim3(256), 0, stream, W, b, Wt);
    hipLaunchKernelGGL(poly_gemm, dim3(KY, MBLK), dim3(256), 0, stream,
                       z, Wt, part, out, two_phase ? 0 : 1);
    if (two_phase)
        hipLaunchKernelGGL(reduce_part, dim3(OUT_ELEMS / 4 / 256), dim3(256), 0,
                           stream, part, out);
}

// Round 8
// 94.734 us; speedup vs baseline: 1.0657x; 1.0403x over previous
//
#include <hip/hip_runtime.h>

// ---------------------------------------------------------------------------
// PolyDecoder: out[4096,64] = polyfeats(z)[4096,37449] @ W^T + b
// f16 MFMA GEMM, A generated on the fly from registers; B double-banked in
// REGISTERS with 8-step-deep prefetch (~1300 cyc cover) — no barriers in the
// K-loop. Two-phase output (nontemporal partial stores + reduce), no atomics.
//
// Padded K layout (32-granular; W padded with zeros):
//   kpad [0,8)=z | 8=const(bias folded) | [9,32)=0 | [32,96)=z^2 |
//   [96,608)=z^3 | [608,4704)=z^4 | [4704,37472)=z^5 | [37472,37504)=0
// step s = kpad/32: 0 deg<=1 | 1..2 deg2 | 3..18 deg3 | 19..146 deg4 |
//                   147..1170 deg5 | 1171 pad
//
// Grid (mb-major, best measured): (MBLK=32 m-blocks of 128 rows) x (KY=21)
//   ky in [0,16):  deg5 slice, sb = 147 + 64*ky, 64 steps (4 sc x 16)
//   ky in [16,20): deg4 slice, sb = 19 + 32*(ky-16), 32 steps (2 sc x 16)
//   ky == 20:      steps 0..18 (deg 0..3), rolled fallback
// Block: 4 waves; wave (g=w>>1, h=w&1): rows [g*64,+64) x cols [h*32,+32)
//   -> 8 mfma_f32_16x16x32_f16 / step; acc 4x2xf32x4 = 32 VGPR.
// B regs: Bk[2][16] half8 = 128 VGPR; ~200 total -> 2 waves/SIMD.
// ---------------------------------------------------------------------------

#define TOTAL_TERMS 37449
#define NSTEP 1172
#define MBLK 32
#define KY 21
#define OUT_ELEMS 262144            // 4096*64

typedef _Float16 half8 __attribute__((ext_vector_type(8)));
typedef float f32x4 __attribute__((ext_vector_type(4)));

// Coalesced tiled transpose W (f32, n-major) -> Wt (f16 fragments).
// Fragment element (s,nt,lane,j) = W[nt*16+(lane&15)][orig(s*32+(lane>>4)*8+j)]
__global__ __launch_bounds__(256) void convert_w(const float* __restrict__ W,
                                                 const float* __restrict__ bias,
                                                 _Float16* __restrict__ Wt) {
    __shared__ _Float16 lds[64][72];
    int tid  = threadIdx.x;
    int lane = tid & 63;
    int nq   = tid >> 6;               // 0..3
    int kb   = blockIdx.x * 64;
    int kp   = kb + lane;

    int o, mode;                       // 0=load W, 1=zero, 2=const+bias
    if (kp < 8)           { o = 1 + kp;            mode = 0; }
    else if (kp == 8)     { o = 0;                 mode = 2; }
    else if (kp < 32)     { o = 0;                 mode = 1; }
    else if (kp < 96)     { o = 9    + (kp - 32);  mode = 0; }
    else if (kp < 608)    { o = 73   + (kp - 96);  mode = 0; }
    else if (kp < 4704)   { o = 585  + (kp - 608); mode = 0; }
    else if (kp < 37472)  { o = 4681 + (kp - 4704);mode = 0; }
    else                  { o = 0;                 mode = 1; }

#pragma unroll
    for (int r = 0; r < 16; ++r) {
        int n = r * 4 + nq;
        const float* wrow = W + (size_t)n * TOTAL_TERMS;
        float v;
        if (mode == 1)      v = 0.f;
        else if (mode == 2) v = wrow[0] + bias[n];
        else                v = wrow[o];             // coalesced along lane
        lds[n][lane] = (_Float16)v;
    }
    __syncthreads();

    int quad = lane >> 4, l16 = lane & 15;
    int n = nq * 16 + l16;
#pragma unroll
    for (int sl = 0; sl < 2; ++sl) {
        int kk = sl * 32 + quad * 8;
        half8 hv;
#pragma unroll
        for (int j = 0; j < 8; ++j) hv[j] = lds[n][kk + j];
        int s = (kb >> 5) + sl;
        *(half8*)(Wt + ((size_t)(s * 4 + nq) * 64 + lane) * 8) = hv;  // coalesced
    }
}

__global__ __launch_bounds__(256, 2) void poly_gemm(const float* __restrict__ z,
                                                    const _Float16* __restrict__ Wt,
                                                    float* __restrict__ part,
                                                    float* __restrict__ out,
                                                    int use_atomic) {
    __shared__ __align__(16) _Float16 zm[128][8];   // sample-major
    __shared__ _Float16 zT[8][144];                 // digit-major

    int tid  = threadIdx.x;
    int lane = tid & 63;
    int w    = tid >> 6;
    int g    = w >> 1;                 // rows [g*64, g*64+64)
    int h    = w & 1;                  // cols [h*32, h*32+32)
    int mb   = blockIdx.x;
    int ky   = blockIdx.y;

    const int sb = (ky < 16) ? (147 + 64 * ky)
                 : (ky < 20) ? (19 + 32 * (ky - 16)) : 0;

    // Per-step B bytes: 4 frags x 1024 B; this wave reads frags 2h, 2h+1.
    const char* gb = (const char*)Wt + (size_t)(sb * 4 + 2 * h) * 1024
                   + (size_t)lane * 16;

    // Prologue: prefetch group 0 (8 steps) into bank 0 BEFORE z staging so
    // its latency overlaps the z loads + barrier.
    half8 Bk[2][16];
    if (ky < 20) {
#pragma unroll
        for (int ii = 0; ii < 8; ++ii)
#pragma unroll
            for (int k = 0; k < 2; ++k)
                Bk[0][ii * 2 + k] = *(const half8*)(gb + ii * 4096 + k * 1024);
    }

    if (tid < 128) {
        const float* zp = z + ((size_t)(mb * 128 + tid)) * 8;
        float4 a = *(const float4*)zp;
        float4 b4 = *(const float4*)(zp + 4);
        half8 hz;
        hz[0] = (_Float16)a.x;  hz[1] = (_Float16)a.y;
        hz[2] = (_Float16)a.z;  hz[3] = (_Float16)a.w;
        hz[4] = (_Float16)b4.x; hz[5] = (_Float16)b4.y;
        hz[6] = (_Float16)b4.z; hz[7] = (_Float16)b4.w;
        *(half8*)&zm[tid][0] = hz;
#pragma unroll
        for (int j = 0; j < 8; ++j) zT[j][tid] = hz[j];
    }
    __syncthreads();

    int quad = lane >> 4;
    int l16  = lane & 15;
    int mrow[4];
    half8 zv[4];
    _Float16 zq[4], zq4[4];
#pragma unroll
    for (int t = 0; t < 4; ++t) {
        mrow[t] = g * 64 + t * 16 + l16;
        zv[t]   = *(const half8*)&zm[mrow[t]][0];
        zq[t]   = zT[quad][mrow[t]];       // z[quad]
        zq4[t]  = zT[quad + 4][mrow[t]];   // z[quad+4]
    }

    f32x4 acc[4][2];
#pragma unroll
    for (int t = 0; t < 4; ++t)
#pragma unroll
        for (int k = 0; k < 2; ++k) acc[t][k] = (f32x4){0.f, 0.f, 0.f, 0.f};

    if (ky < 20) {
        const bool d5     = (ky < 16);
        const int  r2base = d5 ? 4 * ky : 2 * (ky - 16);
        const int  nsc    = d5 ? 4 : 2;            // super-chunks of 16 steps

        _Float16 a1[4];
        if (d5) {
            int r1 = (ky >> 1) & 7;
#pragma unroll
            for (int t = 0; t < 4; ++t) a1[t] = zT[r1][mrow[t]];
        }

        for (int sc = 0; sc < nsc; ++sc) {
            int rtop = (r2base + sc) & 7;
            _Float16 gz[4];
#pragma unroll
            for (int t = 0; t < 4; ++t) {
                _Float16 v = zT[rtop][mrow[t]];
                gz[t] = d5 ? (_Float16)(a1[t] * v) : v;
            }
#pragma unroll
            for (int gp = 0; gp < 2; ++gp) {
                // prefetch next 8-step group into the other bank
                const char* gn = gb + 32768;
#pragma unroll
                for (int ii = 0; ii < 8; ++ii)
#pragma unroll
                    for (int k = 0; k < 2; ++k)
                        Bk[gp ^ 1][ii * 2 + k] =
                            *(const half8*)(gn + ii * 4096 + k * 1024);
                // compute 8 steps from current bank (all indices compile-time)
#pragma unroll
                for (int ii = 0; ii < 8; ++ii) {
                    const int r3 = gp * 4 + (ii >> 1);
                    half8 av[4];
#pragma unroll
                    for (int t = 0; t < 4; ++t) {
                        _Float16 f = gz[t] * zv[t][r3] *
                                     ((ii & 1) ? zq4[t] : zq[t]);
#pragma unroll
                        for (int e = 0; e < 8; ++e) av[t][e] = zv[t][e] * f;
                    }
#pragma unroll
                    for (int t = 0; t < 4; ++t)
#pragma unroll
                        for (int k = 0; k < 2; ++k)
                            acc[t][k] = __builtin_amdgcn_mfma_f32_16x16x32_f16(
                                av[t], Bk[gp][ii * 2 + k], acc[t][k], 0, 0, 0);
                }
                gb += 32768;
            }
        }
    } else {
        // ---- fallback: steps 0..18 (deg 0,2,3), rolled depth-2 ----
        const _Float16* base = Wt + (size_t)h * 1024 + (size_t)lane * 8;
        auto loadB = [&](int s, half8* B) {
            const _Float16* p = base + (size_t)s * 2048;
            B[0] = *(const half8*)p;
            B[1] = *(const half8*)(p + 512);
        };
        auto genA = [&](int s, half8* av) {
            if (s == 0) {
#pragma unroll
                for (int t = 0; t < 4; ++t) {
                    if (quad == 0)      av[t] = zv[t];
                    else if (quad == 1) { av[t] = (half8){}; av[t][0] = (_Float16)1.f; }
                    else                av[t] = (half8){};
                }
                return;
            }
            _Float16 f[4];
            if (s >= 3) {
                int u = s - 3;
                int r1 = (u >> 1) & 7;
                int r2 = ((u & 1) << 2) + quad;
#pragma unroll
                for (int t = 0; t < 4; ++t)
                    f[t] = zT[r1][mrow[t]] * zT[r2][mrow[t]];
            } else {
                int r1 = (s - 1) * 4 + quad;
#pragma unroll
                for (int t = 0; t < 4; ++t)
                    f[t] = zT[r1][mrow[t]];
            }
#pragma unroll
            for (int t = 0; t < 4; ++t)
#pragma unroll
                for (int e = 0; e < 8; ++e) av[t][e] = zv[t][e] * f[t];
        };
        auto mfma8 = [&](const half8* av, const half8* B) {
#pragma unroll
            for (int t = 0; t < 4; ++t)
#pragma unroll
                for (int k = 0; k < 2; ++k)
                    acc[t][k] = __builtin_amdgcn_mfma_f32_16x16x32_f16(
                        av[t], B[k], acc[t][k], 0, 0, 0);
        };

        half8 B0[2], B1[2];
        loadB(0, B0);
        loadB(1, B1);
        int s = 0;
        for (; s + 1 < 19; s += 2) {
            half8 av[4];
            genA(s, av);
            mfma8(av, B0);
            if (s + 2 < 19) loadB(s + 2, B0);
            genA(s + 1, av);
            mfma8(av, B1);
            if (s + 3 < 19) loadB(s + 3, B1);
        }
        {   // s == 18
            half8 av[4];
            genA(18, av);
            mfma8(av, B0);
        }
    }

    // epilogue: C/D layout col=lane&15, row=(lane>>4)*4+reg
    float* dstbase = use_atomic ? out : (part + (size_t)ky * OUT_ELEMS);
#pragma unroll
    for (int t = 0; t < 4; ++t) {
        int mbase = mb * 128 + g * 64 + t * 16 + quad * 4;
#pragma unroll
        for (int k = 0; k < 2; ++k) {
            int col = h * 32 + k * 16 + l16;
#pragma unroll
            for (int r = 0; r < 4; ++r) {
                size_t idx = (size_t)(mbase + r) * 64 + col;
                if (use_atomic) unsafeAtomicAdd(out + idx, acc[t][k][r]);
                else __builtin_nontemporal_store(acc[t][k][r], dstbase + idx);
            }
        }
    }
}

// Phase 2: out[i] = sum_ky part[ky][i]  (vectorized, nontemporal)
__global__ __launch_bounds__(256) void reduce_part(const float* __restrict__ part,
                                                   float* __restrict__ out) {
    int gid = blockIdx.x * 256 + threadIdx.x;      // 65536 float4s
    const f32x4* p4 = (const f32x4*)part;
    f32x4 s = (f32x4){0.f, 0.f, 0.f, 0.f};
#pragma unroll
    for (int j = 0; j < KY; ++j)
        s += __builtin_nontemporal_load(p4 + (size_t)j * (OUT_ELEMS / 4) + gid);
    __builtin_nontemporal_store(s, ((f32x4*)out) + gid);
}

extern "C" void kernel_launch(void* const* d_in, const int* in_sizes, int n_in,
                              void* d_out, int out_size, void* d_ws, size_t ws_size,
                              hipStream_t stream) {
    (void)in_sizes; (void)n_in;
    const float* z = (const float*)d_in[0];
    const float* W = (const float*)d_in[1];
    const float* b = (const float*)d_in[2];
    float* out = (float*)d_out;

    const size_t part_bytes = (size_t)KY * OUT_ELEMS * sizeof(float);  // 22 MB
    const size_t wt_bytes   = (size_t)(NSTEP + 16) * 2048 * sizeof(_Float16);
    const bool two_phase = ws_size >= part_bytes + wt_bytes;

    float* part;
    _Float16* Wt;
    if (two_phase) {
        part = (float*)d_ws;
        Wt   = (_Float16*)((char*)d_ws + part_bytes);
    } else {
        part = out;                    // unused in atomic mode
        Wt   = (_Float16*)d_ws;
    }

    if (!two_phase)
        hipMemsetAsync(d_out, 0, (size_t)out_size * sizeof(float), stream);
    hipLaunchKernelGGL(convert_w, dim3(NSTEP / 2), dim3(256), 0, stream, W, b, Wt);
    hipLaunchKernelGGL(poly_gemm, dim3(MBLK, KY), dim3(256), 0, stream,
                       z, Wt, part, out, two_phase ? 0 : 1);
    if (two_phase)
        hipLaunchKernelGGL(reduce_part, dim3(OUT_ELEMS / 4 / 256), dim3(256), 0,
                           stream, part, out);
}